// Round 14
// baseline (143.085 us; speedup 1.0000x reference)
//
#include <hip/hip_runtime.h>
#include <math.h>

#define NN 8192
#define KDIM 256
#define DD 64
#define NB 4096
#define NBLK 256
#define NTHR 512
#define RPB 32           // rows per block
#define CH 8             // sorted elements per chunk
#define NCH 1024         // chunks
#define LRALPHA 0.2f

__device__ __forceinline__ unsigned f2k(float f) {
    unsigned u = __float_as_uint(f);
    return u ^ ((u >> 31) ? 0xFFFFFFFFu : 0x80000000u);
}
__device__ __forceinline__ float k2f(unsigned k) {
    return __uint_as_float((k & 0x80000000u) ? (k ^ 0x80000000u) : ~k);
}
__device__ __forceinline__ unsigned bucket_of(unsigned key, unsigned kmin, float scale) {
    unsigned d = key - kmin;
    unsigned b = (unsigned)((float)d * scale);
    return b > (NB - 1) ? (NB - 1) : b;
}

// MALL-coherent bypass ops (PROVEN 92.8us in R10): relaxed agent-scope atomics ->
// global_load/store sc0 sc1 (L1/L2 bypass). BATCH-ISSUE loads: N batched loads cost
// ~1 round trip. Do NOT use plain cached loads on cross-block data (R8/R9: +80us
// replay coherence-probe penalty).
__device__ __forceinline__ void  cstf(float* p, float v) { __hip_atomic_store(p, v, __ATOMIC_RELAXED, __HIP_MEMORY_SCOPE_AGENT); }
__device__ __forceinline__ float cldf(const float* p)    { return __hip_atomic_load((float*)p, __ATOMIC_RELAXED, __HIP_MEMORY_SCOPE_AGENT); }
__device__ __forceinline__ float2 cldf2(const float* p) {
    union { unsigned long long u; float2 f; } c;
    c.u = __hip_atomic_load((const unsigned long long*)p, __ATOMIC_RELAXED, __HIP_MEMORY_SCOPE_AGENT);
    return c.f;
}

// All-poll grid barrier: every block publishes its flag then polls ALL flags directly.
// One MALL propagation delay (vs two in the arrive->block0->release scheme of R10).
// Monotone phases; flags zeroed once per launch by memsetAsync.
__device__ __forceinline__ void gridbar(unsigned* flags, unsigned phase) {
    asm volatile("s_waitcnt vmcnt(0)" ::: "memory");   // my bypass stores are visible
    __syncthreads();
    const int t = threadIdx.x;
    if (t == 0)
        __hip_atomic_store(&flags[blockIdx.x], phase, __ATOMIC_RELAXED, __HIP_MEMORY_SCOPE_AGENT);
    if (t < NBLK) {
        while (__hip_atomic_load(&flags[t], __ATOMIC_RELAXED, __HIP_MEMORY_SCOPE_AGENT) < phase)
            __builtin_amdgcn_s_sleep(2);
    }
    __syncthreads();
}

__global__ __launch_bounds__(NTHR, 2) void k_fused(
    const float* __restrict__ h, const float* __restrict__ W,
    const float* __restrict__ a, float* __restrict__ out,
    float* Wh2g, float* sv, float* wnv, float* wpv, float* sg,
    float* cs_neg, float* cs_pos, float* cs_sn, float* cs_sp,
    float* PN, float* SP, float* PNs, float* SPs,
    int* cnt, unsigned* flags)
{
    __shared__ int      ls_bstart[NB + 1];     // persists P1 -> P4
    __shared__ float    ls_wh1[RPB];
    __shared__ float    ls_wh2[RPB];
    __shared__ unsigned ls_ra[8], ls_rb[8];
    __shared__ int      ls_wsum[8];
    __shared__ float    ls_cs[8][2 * DD];      // P2 partials / P3 scan scratch
    __shared__ float    ls_css[16];
    __shared__ float    ls_M2, ls_scale;
    __shared__ unsigned ls_kmin;

    const int t = threadIdx.x, bid = blockIdx.x;
    const int wv = t >> 6, lane = t & 63;
    const int rowBase = bid * RPB;

    // ================= P0: GEMM; rows live in registers until scatter ======
    float myrow[4];
    {
        const int r0 = rowBase + wv * 4;
        float acc0 = 0.f, acc1 = 0.f, acc2 = 0.f, acc3 = 0.f;
        #pragma unroll 2
        for (int k4 = 0; k4 < KDIM / 4; ++k4) {
            float w0 = W[(4 * k4 + 0) * DD + lane];
            float w1 = W[(4 * k4 + 1) * DD + lane];
            float w2 = W[(4 * k4 + 2) * DD + lane];
            float w3 = W[(4 * k4 + 3) * DD + lane];
            float4 h0 = *(const float4*)(h + (size_t)(r0 + 0) * KDIM + 4 * k4);
            float4 h1 = *(const float4*)(h + (size_t)(r0 + 1) * KDIM + 4 * k4);
            float4 h2 = *(const float4*)(h + (size_t)(r0 + 2) * KDIM + 4 * k4);
            float4 h3 = *(const float4*)(h + (size_t)(r0 + 3) * KDIM + 4 * k4);
            acc0 = fmaf(h0.x, w0, acc0); acc0 = fmaf(h0.y, w1, acc0);
            acc0 = fmaf(h0.z, w2, acc0); acc0 = fmaf(h0.w, w3, acc0);
            acc1 = fmaf(h1.x, w0, acc1); acc1 = fmaf(h1.y, w1, acc1);
            acc1 = fmaf(h1.z, w2, acc1); acc1 = fmaf(h1.w, w3, acc1);
            acc2 = fmaf(h2.x, w0, acc2); acc2 = fmaf(h2.y, w1, acc2);
            acc2 = fmaf(h2.z, w2, acc2); acc2 = fmaf(h2.w, w3, acc2);
            acc3 = fmaf(h3.x, w0, acc3); acc3 = fmaf(h3.y, w1, acc3);
            acc3 = fmaf(h3.z, w2, acc3); acc3 = fmaf(h3.w, w3, acc3);
        }
        myrow[0] = acc0; myrow[1] = acc1; myrow[2] = acc2; myrow[3] = acc3;
        float a1 = a[lane], a2 = a[DD + lane];
        #pragma unroll
        for (int i = 0; i < 4; ++i) {
            float r1 = myrow[i] * a1, r2 = myrow[i] * a2;
            #pragma unroll
            for (int off = 32; off > 0; off >>= 1) {
                r1 += __shfl_xor(r1, off, 64);
                r2 += __shfl_xor(r2, off, 64);
            }
            if (lane == 0) {
                cstf(&Wh2g[r0 + i], r2);
                ls_wh1[wv * 4 + i] = r1;
                ls_wh2[wv * 4 + i] = r2;
            }
        }
    }
    gridbar(flags, 1);

    // ================= P1: redundant minmax+hist+scan (LDS) + scatter =================
    for (int i = t; i < NB; i += NTHR) ls_bstart[i] = 0;
    float v16[16];
    #pragma unroll
    for (int q = 0; q < 8; ++q) {                   // batch-issue 8 paired bypass loads
        float2 p2 = cldf2(&Wh2g[t * 16 + 2 * q]);
        v16[2 * q] = p2.x; v16[2 * q + 1] = p2.y;
    }
    {
        unsigned lmin = 0xFFFFFFFFu, lmax = 0u;
        #pragma unroll
        for (int q = 0; q < 16; ++q) {
            unsigned k = f2k(v16[q]);
            lmin = min(lmin, k); lmax = max(lmax, k);
        }
        #pragma unroll
        for (int off = 32; off > 0; off >>= 1) {
            lmin = min(lmin, (unsigned)__shfl_xor((int)lmin, off, 64));
            lmax = max(lmax, (unsigned)__shfl_xor((int)lmax, off, 64));
        }
        if (lane == 0) { ls_ra[wv] = lmin; ls_rb[wv] = lmax; }
    }
    __syncthreads();
    if (t == 0) {
        unsigned mn = ls_ra[0], mx = ls_rb[0];
        for (int i = 1; i < 8; ++i) { mn = min(mn, ls_ra[i]); mx = max(mx, ls_rb[i]); }
        ls_kmin = mn;
        ls_scale = (float)NB / ((float)(mx - mn) + 1.0f);
        ls_M2 = k2f(mx);
    }
    __syncthreads();
    const unsigned kmin = ls_kmin;
    const float scale = ls_scale;
    const float M2 = ls_M2;

    #pragma unroll
    for (int q = 0; q < 16; ++q)
        atomicAdd(&ls_bstart[bucket_of(f2k(v16[q]), kmin, scale)], 1);
    __syncthreads();
    {
        int s[8]; int tot = 0;
        #pragma unroll
        for (int j = 0; j < 8; ++j) { s[j] = ls_bstart[8 * t + j]; tot += s[j]; }
        int x = tot;
        #pragma unroll
        for (int off = 1; off < 64; off <<= 1) {
            int y = __shfl_up(x, off, 64);
            if (lane >= off) x += y;
        }
        if (lane == 63) ls_wsum[wv] = x;
        __syncthreads();
        int woff = 0;
        for (int w2 = 0; w2 < wv; ++w2) woff += ls_wsum[w2];
        int acc = woff + x - tot;
        #pragma unroll
        for (int j = 0; j < 8; ++j) { ls_bstart[8 * t + j] = acc; acc += s[j]; }
        if (t == 0) ls_bstart[NB] = NN;
    }
    __syncthreads();
    // scatter: lanes 0-3 issue the 4 cursor RMWs concurrently; rows from registers
    {
        int posl = 0;
        if (lane < 4) {
            unsigned b = bucket_of(f2k(ls_wh2[wv * 4 + lane]), kmin, scale);
            posl = ls_bstart[b] + atomicAdd(&cnt[b], 1);
        }
        #pragma unroll
        for (int i = 0; i < 4; ++i) {
            int lr = wv * 4 + i;
            float x = ls_wh2[lr];
            int pos = __shfl(posl, i, 64);
            cstf(&sg[(size_t)pos * DD + lane], myrow[i]);
            if (lane == 0) {
                cstf(&sv[pos], x);
                cstf(&wnv[pos], expf(LRALPHA * (x - M2)));   // <= 1
                cstf(&wpv[pos], expf(x - M2));               // <= 1
            }
        }
    }
    gridbar(flags, 2);

    // ================= P2: chunk sums — CH=8; block's 32 rows = 4 chunks =============
    {
        int base = rowBase + wv * 4;                // wave's 4 elements = half of chunk (wv>>1)
        float g4[4], wn4[4], wp4[4];
        #pragma unroll
        for (int kk = 0; kk < 4; ++kk) {            // batch-issue 12 bypass loads
            int k = base + kk;
            g4[kk]  = cldf(&sg[(size_t)k * DD + lane]);
            wn4[kk] = cldf(&wnv[k]);
            wp4[kk] = cldf(&wpv[k]);
        }
        float an = 0.f, ap = 0.f, sn = 0.f, sp = 0.f;
        #pragma unroll
        for (int kk = 0; kk < 4; ++kk) {
            an = fmaf(wn4[kk], g4[kk], an); ap = fmaf(wp4[kk], g4[kk], ap);
            sn += wn4[kk]; sp += wp4[kk];
        }
        ls_cs[wv][lane] = an; ls_cs[wv][DD + lane] = ap;
        if (lane == 0) { ls_css[wv] = sn; ls_css[8 + wv] = sp; }
        __syncthreads();
        if (wv < 4) {                               // chunk c = bid*4 + wv (neg side)
            int c = bid * 4 + wv;
            float s = ls_cs[2 * wv][lane] + ls_cs[2 * wv + 1][lane];
            cstf(&cs_neg[(size_t)c * DD + lane], s);
            if (lane == 0) cstf(&cs_sn[c], ls_css[2 * wv] + ls_css[2 * wv + 1]);
        } else {                                    // chunk c = bid*4 + (wv-4) (pos side)
            int cw = wv - 4;
            int c = bid * 4 + cw;
            float s = ls_cs[2 * cw][DD + lane] + ls_cs[2 * cw + 1][DD + lane];
            cstf(&cs_pos[(size_t)c * DD + lane], s);
            if (lane == 0) cstf(&cs_sp[c], ls_css[8 + 2 * cw] + ls_css[8 + 2 * cw + 1]);
        }
    }
    gridbar(flags, 3);

    // ================= P3: blocks 0-2 scan the 1024 chunk sums =================
    if (bid == 0) {
        // exclusive prefix of cs_neg -> PN[0..1024]; wave owns 128 chunks
        const int c0 = wv * 128;
        float v[128];
        #pragma unroll
        for (int j = 0; j < 128; ++j) v[j] = cldf(&cs_neg[(size_t)(c0 + j) * DD + lane]);
        float tot = 0.f;
        #pragma unroll
        for (int j = 0; j < 128; ++j) tot += v[j];
        ls_cs[wv][lane] = tot;
        __syncthreads();
        float acc = 0.f;
        for (int w2 = 0; w2 < wv; ++w2) acc += ls_cs[w2][lane];
        #pragma unroll
        for (int j = 0; j < 128; ++j) { cstf(&PN[(size_t)(c0 + j) * DD + lane], acc); acc += v[j]; }
        if (wv == 7) cstf(&PN[(size_t)NCH * DD + lane], acc);
    } else if (bid == 1) {
        // inclusive suffix of cs_pos -> SP[0..1024]
        const int c0 = wv * 128;
        float v[128];
        #pragma unroll
        for (int j = 0; j < 128; ++j) v[j] = cldf(&cs_pos[(size_t)(c0 + j) * DD + lane]);
        float tot = 0.f;
        #pragma unroll
        for (int j = 0; j < 128; ++j) tot += v[j];
        ls_cs[wv][lane] = tot;
        __syncthreads();
        float acc = 0.f;
        for (int w2 = wv + 1; w2 < 8; ++w2) acc += ls_cs[w2][lane];
        #pragma unroll
        for (int j = 127; j >= 0; --j) { acc += v[j]; cstf(&SP[(size_t)(c0 + j) * DD + lane], acc); }
        if (wv == 7) cstf(&SP[(size_t)NCH * DD + lane], 0.f);
    } else if (bid == 2) {
        if (wv == 0) {          // scalar prefix over 1024: lane owns 16
            float s[16];
            #pragma unroll
            for (int j = 0; j < 16; ++j) s[j] = cldf(&cs_sn[16 * lane + j]);
            float tot = 0.f;
            #pragma unroll
            for (int j = 0; j < 16; ++j) tot += s[j];
            float x = tot;
            #pragma unroll
            for (int off = 1; off < 64; off <<= 1) {
                float y = __shfl_up(x, off, 64);
                if (lane >= off) x += y;
            }
            float acc = x - tot;
            #pragma unroll
            for (int j = 0; j < 16; ++j) { cstf(&PNs[16 * lane + j], acc); acc += s[j]; }
            if (lane == 63) cstf(&PNs[NCH], acc);
        } else if (wv == 1) {   // scalar suffix over 1024
            float s[16];
            #pragma unroll
            for (int j = 0; j < 16; ++j) s[j] = cldf(&cs_sp[16 * lane + j]);
            float tot = 0.f;
            #pragma unroll
            for (int j = 0; j < 16; ++j) tot += s[j];
            float x = tot;
            #pragma unroll
            for (int off = 1; off < 64; off <<= 1) {
                float y = __shfl_down(x, off, 64);
                if (lane < 64 - off) x += y;
            }
            float acc = x - tot;   // sum over lanes > lane
            #pragma unroll
            for (int j = 15; j >= 0; --j) { acc += s[j]; cstf(&SPs[16 * lane + j], acc); }
            if (lane == 63) cstf(&SPs[NCH], 0.f);
        }
    }
    gridbar(flags, 4);

    // ================= P4: output — batched headers + short (CH=8) window loops =======
    int c0f4[4], c1e4[4];
    #pragma unroll
    for (int i = 0; i < 4; ++i) {
        float tt = -ls_wh1[wv * 4 + i];
        unsigned kt = f2k(tt);
        int p0 = 0, p1 = 0;
        if (kt >= kmin) {
            unsigned b = bucket_of(kt, kmin, scale);
            p0 = ls_bstart[b]; p1 = ls_bstart[b + 1];
        }
        c0f4[i] = p0 >> 3;            // CH = 8
        c1e4[i] = (p1 + 7) >> 3;
    }
    float pn4[4], sp4[4], pns4[4], sps4[4];
    #pragma unroll
    for (int i = 0; i < 4; ++i) {                   // batch-issue 16 header loads
        pn4[i]  = cldf(&PN[(size_t)c0f4[i] * DD + lane]);
        sp4[i]  = cldf(&SP[(size_t)c1e4[i] * DD + lane]);
        pns4[i] = cldf(&PNs[c0f4[i]]);
        sps4[i] = cldf(&SPs[c1e4[i]]);
    }
    #pragma unroll
    for (int i = 0; i < 4; ++i) {
        int row = rowBase + wv * 4 + i;
        float w1 = ls_wh1[wv * 4 + i];
        float z = w1 + M2;                          // max_j (Wh1_i + Wh2_j)
        float m = (z >= 0.f) ? z : LRALPHA * z;     // lrelu(z) = exact row max
        float c1 = expf(z - m);                     // exponent <= 0
        float c2 = expf(LRALPHA * z - m);           // exponent <= 0
        float tt = -w1;
        float nn_ = pn4[i], dn_ = pns4[i];
        float np_ = sp4[i], dp_ = sps4[i];
        // window is CH-aligned (8): typically 8-16 elements -> 1-2 batches
        for (int base2 = c0f4[i] * CH; base2 < c1e4[i] * CH; base2 += 8) {
            float sv8[8], wn8[8], wp8[8], g8[8];
            #pragma unroll
            for (int jj = 0; jj < 8; ++jj) {        // batch-issue 32 loads
                int k = base2 + jj;
                sv8[jj] = cldf(&sv[k]);
                wn8[jj] = cldf(&wnv[k]);
                wp8[jj] = cldf(&wpv[k]);
                g8[jj]  = cldf(&sg[(size_t)k * DD + lane]);
            }
            #pragma unroll
            for (int jj = 0; jj < 8; ++jj) {
                if (sv8[jj] <= tt) { nn_ = fmaf(wn8[jj], g8[jj], nn_); dn_ += wn8[jj]; }
                else               { np_ = fmaf(wp8[jj], g8[jj], np_); dp_ += wp8[jj]; }
            }
        }
        float num = c2 * nn_ + c1 * np_;
        float den = c2 * dn_ + c1 * dp_;
        float r = num / den;
        out[(size_t)row * DD + lane] = (r > 0.f) ? r : expm1f(r);   // elu
    }
}

extern "C" void kernel_launch(void* const* d_in, const int* in_sizes, int n_in,
                              void* d_out, int out_size, void* d_ws, size_t ws_size,
                              hipStream_t stream)
{
    const float* h = (const float*)d_in[0];
    // d_in[1] = adj (bool, unused by the reference computation)
    const float* W = (const float*)d_in[2];
    const float* a = (const float*)d_in[3];
    float* out = (float*)d_out;
    float* ws = (float*)d_ws;

    float* Wh2g   = ws;                              // NN
    float* sv     = Wh2g + NN;                       // NN
    float* wnv    = sv + NN;                         // NN
    float* wpv    = wnv + NN;                        // NN
    float* sg     = wpv + NN;                        // NN*DD (sorted Wh rows)
    float* cs_neg = sg + (size_t)NN * DD;            // NCH*DD
    float* cs_pos = cs_neg + (size_t)NCH * DD;       // NCH*DD
    float* cs_sn  = cs_pos + (size_t)NCH * DD;       // NCH (pad 1088)
    float* cs_sp  = cs_sn + 1088;                    // NCH (pad 1088)
    float* PN     = cs_sp + 1088;                    // (NCH+1)*DD
    float* SP     = PN + (size_t)(NCH + 1) * DD;     // (NCH+1)*DD
    float* PNs    = SP + (size_t)(NCH + 1) * DD;     // NCH+1 (pad 1088)
    float* SPs    = PNs + 1088;                      // NCH+1 (pad 1088)
    unsigned* flags = (unsigned*)(SPs + 1088);       // NBLK
    int*   cnt    = (int*)(flags + NBLK);            // NB cursors (must start at 0)

    // zero flags + cnt in one captured async memset
    hipMemsetAsync(flags, 0, (NBLK + NB) * sizeof(unsigned), stream);
    k_fused<<<NBLK, NTHR, 0, stream>>>(h, W, a, out,
        Wh2g, sv, wnv, wpv, sg,
        cs_neg, cs_pos, cs_sn, cs_sp,
        PN, SP, PNs, SPs,
        cnt, flags);
}

// Round 15
// 92.063 us; speedup vs baseline: 1.5542x; 1.5542x over previous
//
#include <hip/hip_runtime.h>
#include <math.h>

#define NN 8192
#define KDIM 256
#define DD 64
#define NB 4096
#define NBLK 256
#define NTHR 512
#define RPB 32           // rows per block
#define CH 32            // sorted elements per chunk (= rows per block)
#define NCH 256          // chunks
#define LRALPHA 0.2f

__device__ __forceinline__ unsigned f2k(float f) {
    unsigned u = __float_as_uint(f);
    return u ^ ((u >> 31) ? 0xFFFFFFFFu : 0x80000000u);
}
__device__ __forceinline__ float k2f(unsigned k) {
    return __uint_as_float((k & 0x80000000u) ? (k ^ 0x80000000u) : ~k);
}
__device__ __forceinline__ unsigned bucket_of(unsigned key, unsigned kmin, float scale) {
    unsigned d = key - kmin;
    unsigned b = (unsigned)((float)d * scale);
    return b > (NB - 1) ? (NB - 1) : b;
}

// MALL-coherent bypass ops (PROVEN 92.8us in R10): relaxed agent-scope atomics ->
// global_load/store sc0 sc1 (L1/L2 bypass). BATCH-ISSUE loads: N batched loads cost
// ~1 round trip. Do NOT use plain cached loads on cross-block data (R8/R9: +80us
// replay coherence-probe penalty). Do NOT use all-poll barriers (R14: 256x poll
// contention, +50us).
__device__ __forceinline__ void  cstf(float* p, float v) { __hip_atomic_store(p, v, __ATOMIC_RELAXED, __HIP_MEMORY_SCOPE_AGENT); }
__device__ __forceinline__ float cldf(const float* p)    { return __hip_atomic_load((float*)p, __ATOMIC_RELAXED, __HIP_MEMORY_SCOPE_AGENT); }

// Fence-free two-stage grid barrier (proven R5/R7/R10).
__device__ __forceinline__ void gridbar(unsigned* flags, unsigned* rel, unsigned phase) {
    asm volatile("s_waitcnt vmcnt(0)" ::: "memory");
    __syncthreads();
    const int t = threadIdx.x;
    if (blockIdx.x == 0) {
        if (t == 0)
            __hip_atomic_store(&flags[0], phase, __ATOMIC_RELAXED, __HIP_MEMORY_SCOPE_AGENT);
        if (t < NBLK) {
            while (__hip_atomic_load(&flags[t], __ATOMIC_RELAXED, __HIP_MEMORY_SCOPE_AGENT) < phase)
                __builtin_amdgcn_s_sleep(1);
        }
        __syncthreads();
        if (t == 0)
            __hip_atomic_store(rel, phase, __ATOMIC_RELAXED, __HIP_MEMORY_SCOPE_AGENT);
    } else {
        if (t == 0) {
            __hip_atomic_store(&flags[blockIdx.x], phase, __ATOMIC_RELAXED, __HIP_MEMORY_SCOPE_AGENT);
            while (__hip_atomic_load(rel, __ATOMIC_RELAXED, __HIP_MEMORY_SCOPE_AGENT) < phase)
                __builtin_amdgcn_s_sleep(1);
        }
        __syncthreads();
    }
}

__global__ __launch_bounds__(NTHR, 2) void k_fused(
    const float* __restrict__ h, const float* __restrict__ W,
    const float* __restrict__ a, float* __restrict__ out,
    float* Wh2g, float* sv, float* wnv, float* wpv, float* sg,
    float* cs_neg, float* cs_pos, float* cs_sn, float* cs_sp,
    float* PN, float* SP, float* PNs, float* SPs,
    int* cnt, unsigned* flags, unsigned* rel)
{
    __shared__ int      ls_bstart[NB + 1];     // persists P1 -> P4
    __shared__ float    ls_wh1[RPB];
    __shared__ float    ls_wh2[RPB];
    __shared__ unsigned ls_ra[8], ls_rb[8];
    __shared__ int      ls_wsum[8];
    __shared__ float    ls_cs[8][2 * DD];      // P2 reduce / P3 scan scratch
    __shared__ float    ls_css[16];
    __shared__ float    ls_M2, ls_scale;
    __shared__ unsigned ls_kmin;

    const int t = threadIdx.x, bid = blockIdx.x;
    const int wv = t >> 6, lane = t & 63;
    const int rowBase = bid * RPB;

    // ================= P0: GEMM; rows live in registers until scatter ======
    float myrow[4];
    {
        const int r0 = rowBase + wv * 4;
        float acc0 = 0.f, acc1 = 0.f, acc2 = 0.f, acc3 = 0.f;
        #pragma unroll 2
        for (int k4 = 0; k4 < KDIM / 4; ++k4) {
            float w0 = W[(4 * k4 + 0) * DD + lane];
            float w1 = W[(4 * k4 + 1) * DD + lane];
            float w2 = W[(4 * k4 + 2) * DD + lane];
            float w3 = W[(4 * k4 + 3) * DD + lane];
            float4 h0 = *(const float4*)(h + (size_t)(r0 + 0) * KDIM + 4 * k4);
            float4 h1 = *(const float4*)(h + (size_t)(r0 + 1) * KDIM + 4 * k4);
            float4 h2 = *(const float4*)(h + (size_t)(r0 + 2) * KDIM + 4 * k4);
            float4 h3 = *(const float4*)(h + (size_t)(r0 + 3) * KDIM + 4 * k4);
            acc0 = fmaf(h0.x, w0, acc0); acc0 = fmaf(h0.y, w1, acc0);
            acc0 = fmaf(h0.z, w2, acc0); acc0 = fmaf(h0.w, w3, acc0);
            acc1 = fmaf(h1.x, w0, acc1); acc1 = fmaf(h1.y, w1, acc1);
            acc1 = fmaf(h1.z, w2, acc1); acc1 = fmaf(h1.w, w3, acc1);
            acc2 = fmaf(h2.x, w0, acc2); acc2 = fmaf(h2.y, w1, acc2);
            acc2 = fmaf(h2.z, w2, acc2); acc2 = fmaf(h2.w, w3, acc2);
            acc3 = fmaf(h3.x, w0, acc3); acc3 = fmaf(h3.y, w1, acc3);
            acc3 = fmaf(h3.z, w2, acc3); acc3 = fmaf(h3.w, w3, acc3);
        }
        myrow[0] = acc0; myrow[1] = acc1; myrow[2] = acc2; myrow[3] = acc3;
        float a1 = a[lane], a2 = a[DD + lane];
        #pragma unroll
        for (int i = 0; i < 4; ++i) {
            float r1 = myrow[i] * a1, r2 = myrow[i] * a2;
            #pragma unroll
            for (int off = 32; off > 0; off >>= 1) {
                r1 += __shfl_xor(r1, off, 64);
                r2 += __shfl_xor(r2, off, 64);
            }
            if (lane == 0) {
                cstf(&Wh2g[r0 + i], r2);
                ls_wh1[wv * 4 + i] = r1;
                ls_wh2[wv * 4 + i] = r2;
            }
        }
    }
    gridbar(flags, rel, 1);

    // ================= P1: redundant minmax+hist+scan (LDS) + scatter =================
    for (int i = t; i < NB; i += NTHR) ls_bstart[i] = 0;
    float v16[16];
    #pragma unroll
    for (int q = 0; q < 16; ++q)                    // batch-issue 16 bypass loads
        v16[q] = cldf(&Wh2g[t + q * NTHR]);
    {
        unsigned lmin = 0xFFFFFFFFu, lmax = 0u;
        #pragma unroll
        for (int q = 0; q < 16; ++q) {
            unsigned k = f2k(v16[q]);
            lmin = min(lmin, k); lmax = max(lmax, k);
        }
        #pragma unroll
        for (int off = 32; off > 0; off >>= 1) {
            lmin = min(lmin, (unsigned)__shfl_xor((int)lmin, off, 64));
            lmax = max(lmax, (unsigned)__shfl_xor((int)lmax, off, 64));
        }
        if (lane == 0) { ls_ra[wv] = lmin; ls_rb[wv] = lmax; }
    }
    __syncthreads();
    if (t == 0) {
        unsigned mn = ls_ra[0], mx = ls_rb[0];
        for (int i = 1; i < 8; ++i) { mn = min(mn, ls_ra[i]); mx = max(mx, ls_rb[i]); }
        ls_kmin = mn;
        ls_scale = (float)NB / ((float)(mx - mn) + 1.0f);
        ls_M2 = k2f(mx);
    }
    __syncthreads();
    const unsigned kmin = ls_kmin;
    const float scale = ls_scale;
    const float M2 = ls_M2;

    #pragma unroll
    for (int q = 0; q < 16; ++q)
        atomicAdd(&ls_bstart[bucket_of(f2k(v16[q]), kmin, scale)], 1);
    __syncthreads();
    {
        int s[8]; int tot = 0;
        #pragma unroll
        for (int j = 0; j < 8; ++j) { s[j] = ls_bstart[8 * t + j]; tot += s[j]; }
        int x = tot;
        #pragma unroll
        for (int off = 1; off < 64; off <<= 1) {
            int y = __shfl_up(x, off, 64);
            if (lane >= off) x += y;
        }
        if (lane == 63) ls_wsum[wv] = x;
        __syncthreads();
        int woff = 0;
        for (int w2 = 0; w2 < wv; ++w2) woff += ls_wsum[w2];
        int acc = woff + x - tot;
        #pragma unroll
        for (int j = 0; j < 8; ++j) { ls_bstart[8 * t + j] = acc; acc += s[j]; }
        if (t == 0) ls_bstart[NB] = NN;
    }
    __syncthreads();
    // scatter: lanes 0-3 issue the 4 cursor RMWs concurrently; rows from registers
    {
        int posl = 0;
        if (lane < 4) {
            unsigned b = bucket_of(f2k(ls_wh2[wv * 4 + lane]), kmin, scale);
            posl = ls_bstart[b] + atomicAdd(&cnt[b], 1);
        }
        #pragma unroll
        for (int i = 0; i < 4; ++i) {
            int lr = wv * 4 + i;
            float x = ls_wh2[lr];
            int pos = __shfl(posl, i, 64);
            cstf(&sg[(size_t)pos * DD + lane], myrow[i]);
            if (lane == 0) {
                cstf(&sv[pos], x);
                cstf(&wnv[pos], expf(LRALPHA * (x - M2)));   // <= 1
                cstf(&wpv[pos], expf(x - M2));               // <= 1
            }
        }
    }
    gridbar(flags, rel, 2);

    // ================= P2: chunk sums — chunk bid = sorted rows [32*bid, 32*bid+32) ==
    {
        int base = bid * CH + wv * 4;
        float g4[4], wn4[4], wp4[4];
        #pragma unroll
        for (int kk = 0; kk < 4; ++kk) {            // batch-issue 12 loads
            int k = base + kk;
            g4[kk]  = cldf(&sg[(size_t)k * DD + lane]);
            wn4[kk] = cldf(&wnv[k]);
            wp4[kk] = cldf(&wpv[k]);
        }
        float an = 0.f, ap = 0.f, sn = 0.f, sp = 0.f;
        #pragma unroll
        for (int kk = 0; kk < 4; ++kk) {
            an = fmaf(wn4[kk], g4[kk], an); ap = fmaf(wp4[kk], g4[kk], ap);
            sn += wn4[kk]; sp += wp4[kk];
        }
        ls_cs[wv][lane] = an; ls_cs[wv][DD + lane] = ap;
        if (lane == 0) { ls_css[wv] = sn; ls_css[8 + wv] = sp; }
        __syncthreads();
        if (wv == 0) {
            float s = 0.f;
            #pragma unroll
            for (int w2 = 0; w2 < 8; ++w2) s += ls_cs[w2][lane];
            cstf(&cs_neg[bid * DD + lane], s);
            if (lane == 0) { float ss = 0.f; for (int w2 = 0; w2 < 8; ++w2) ss += ls_css[w2]; cstf(&cs_sn[bid], ss); }
        } else if (wv == 1) {
            float s = 0.f;
            #pragma unroll
            for (int w2 = 0; w2 < 8; ++w2) s += ls_cs[w2][DD + lane];
            cstf(&cs_pos[bid * DD + lane], s);
            if (lane == 0) { float ss = 0.f; for (int w2 = 0; w2 < 8; ++w2) ss += ls_css[8 + w2]; cstf(&cs_sp[bid], ss); }
        }
    }
    gridbar(flags, rel, 3);

    // ================= P3: blocks 0-2 scan; ALL blocks precompute corrections =========
    // (corrections depend only on sv/wnv/wpv/sg — final since barrier 2 — so blocks
    //  3-255 overlap them with blocks 0-2's serial scans instead of idling)
    if (bid == 0) {
        // exclusive prefix of neg-weighted chunk vectors -> PN[0..256]
        const int c0 = wv * 32;
        float v[32];
        #pragma unroll
        for (int j = 0; j < 32; ++j) v[j] = cldf(&cs_neg[(c0 + j) * DD + lane]);  // batch
        float tot = 0.f;
        #pragma unroll
        for (int j = 0; j < 32; ++j) tot += v[j];
        ls_cs[wv][lane] = tot;
        __syncthreads();
        float acc = 0.f;
        for (int w2 = 0; w2 < wv; ++w2) acc += ls_cs[w2][lane];
        #pragma unroll
        for (int j = 0; j < 32; ++j) { cstf(&PN[(c0 + j) * DD + lane], acc); acc += v[j]; }
        if (wv == 7) cstf(&PN[NCH * DD + lane], acc);
    } else if (bid == 1) {
        // inclusive suffix of pos-weighted chunk vectors -> SP[0..256]
        const int c0 = wv * 32;
        float v[32];
        #pragma unroll
        for (int j = 0; j < 32; ++j) v[j] = cldf(&cs_pos[(c0 + j) * DD + lane]);  // batch
        float tot = 0.f;
        #pragma unroll
        for (int j = 0; j < 32; ++j) tot += v[j];
        ls_cs[wv][lane] = tot;
        __syncthreads();
        float acc = 0.f;
        for (int w2 = wv + 1; w2 < 8; ++w2) acc += ls_cs[w2][lane];
        #pragma unroll
        for (int j = 31; j >= 0; --j) { acc += v[j]; cstf(&SP[(c0 + j) * DD + lane], acc); }
        if (wv == 7) cstf(&SP[NCH * DD + lane], 0.f);
    } else if (bid == 2) {
        if (wv == 0) {          // scalar prefix
            float s[4];
            #pragma unroll
            for (int j = 0; j < 4; ++j) s[j] = cldf(&cs_sn[4 * lane + j]);
            float tot = s[0] + s[1] + s[2] + s[3];
            float x = tot;
            #pragma unroll
            for (int off = 1; off < 64; off <<= 1) {
                float y = __shfl_up(x, off, 64);
                if (lane >= off) x += y;
            }
            float acc = x - tot;
            #pragma unroll
            for (int j = 0; j < 4; ++j) { cstf(&PNs[4 * lane + j], acc); acc += s[j]; }
            if (lane == 63) cstf(&PNs[NCH], acc);
        } else if (wv == 1) {   // scalar suffix
            float s[4];
            #pragma unroll
            for (int j = 0; j < 4; ++j) s[j] = cldf(&cs_sp[4 * lane + j]);
            float tot = s[0] + s[1] + s[2] + s[3];
            float x = tot;
            #pragma unroll
            for (int off = 1; off < 64; off <<= 1) {
                float y = __shfl_down(x, off, 64);
                if (lane < 64 - off) x += y;
            }
            float acc = x - tot;   // sum over lanes > lane
            #pragma unroll
            for (int j = 3; j >= 0; --j) { acc += s[j]; cstf(&SPs[4 * lane + j], acc); }
            if (lane == 63) cstf(&SPs[NCH], 0.f);
        }
    }
    // ---- correction precompute (all blocks; overlaps blocks 0-2's scans) ----
    int c0f4[4], c1e4[4];
    float cn4[4], dn4[4], cp4[4], dp4[4];
    #pragma unroll
    for (int i = 0; i < 4; ++i) {
        float tt = -ls_wh1[wv * 4 + i];
        unsigned kt = f2k(tt);
        int p0 = 0, p1 = 0;
        if (kt >= kmin) {
            unsigned b = bucket_of(kt, kmin, scale);
            p0 = ls_bstart[b]; p1 = ls_bstart[b + 1];
        }
        int c0f = p0 >> 5, c1e = (p1 + 31) >> 5;     // CH = 32
        c0f4[i] = c0f; c1e4[i] = c1e;
        float nn_ = 0.f, dn_ = 0.f, np_ = 0.f, dp_ = 0.f;
        for (int base2 = c0f * CH; base2 < c1e * CH; base2 += 8) {
            float sv8[8], wn8[8], wp8[8], g8[8];
            #pragma unroll
            for (int jj = 0; jj < 8; ++jj) {        // batch-issue 32 loads
                int k = base2 + jj;
                sv8[jj] = cldf(&sv[k]);
                wn8[jj] = cldf(&wnv[k]);
                wp8[jj] = cldf(&wpv[k]);
                g8[jj]  = cldf(&sg[(size_t)k * DD + lane]);
            }
            #pragma unroll
            for (int jj = 0; jj < 8; ++jj) {
                if (sv8[jj] <= tt) { nn_ = fmaf(wn8[jj], g8[jj], nn_); dn_ += wn8[jj]; }
                else               { np_ = fmaf(wp8[jj], g8[jj], np_); dp_ += wp8[jj]; }
            }
        }
        cn4[i] = nn_; dn4[i] = dn_; cp4[i] = np_; dp4[i] = dp_;
    }
    gridbar(flags, rel, 4);

    // ================= P4: finalize — batched headers + math only =================
    float pn4[4], sp4[4], pns4[4], sps4[4];
    #pragma unroll
    for (int i = 0; i < 4; ++i) {                   // batch-issue 16 header loads
        pn4[i]  = cldf(&PN[c0f4[i] * DD + lane]);
        sp4[i]  = cldf(&SP[c1e4[i] * DD + lane]);
        pns4[i] = cldf(&PNs[c0f4[i]]);
        sps4[i] = cldf(&SPs[c1e4[i]]);
    }
    #pragma unroll
    for (int i = 0; i < 4; ++i) {
        int row = rowBase + wv * 4 + i;
        float w1 = ls_wh1[wv * 4 + i];
        float z = w1 + M2;                          // max_j (Wh1_i + Wh2_j)
        float m = (z >= 0.f) ? z : LRALPHA * z;     // lrelu(z) = exact row max
        float c1 = expf(z - m);                     // exponent <= 0
        float c2 = expf(LRALPHA * z - m);           // exponent <= 0
        float num = c2 * (pn4[i] + cn4[i]) + c1 * (sp4[i] + cp4[i]);
        float den = c2 * (pns4[i] + dn4[i]) + c1 * (sps4[i] + dp4[i]);
        float r = num / den;
        out[(size_t)row * DD + lane] = (r > 0.f) ? r : expm1f(r);   // elu
    }
}

extern "C" void kernel_launch(void* const* d_in, const int* in_sizes, int n_in,
                              void* d_out, int out_size, void* d_ws, size_t ws_size,
                              hipStream_t stream)
{
    const float* h = (const float*)d_in[0];
    // d_in[1] = adj (bool, unused by the reference computation)
    const float* W = (const float*)d_in[2];
    const float* a = (const float*)d_in[3];
    float* out = (float*)d_out;
    float* ws = (float*)d_ws;

    float* Wh2g   = ws;                              // NN
    float* sv     = Wh2g + NN;                       // NN
    float* wnv    = sv + NN;                         // NN
    float* wpv    = wnv + NN;                        // NN
    float* sg     = wpv + NN;                        // NN*DD (sorted Wh rows)
    float* cs_neg = sg + (size_t)NN * DD;            // NCH*DD
    float* cs_pos = cs_neg + NCH * DD;               // NCH*DD
    float* cs_sn  = cs_pos + NCH * DD;               // NCH
    float* cs_sp  = cs_sn + NCH;                     // NCH
    float* PN     = cs_sp + NCH;                     // (NCH+1)*DD
    float* SP     = PN + (NCH + 1) * DD;             // (NCH+1)*DD
    float* PNs    = SP + (NCH + 1) * DD;             // NCH+1 (pad 320)
    float* SPs    = PNs + 320;                       // NCH+1 (pad 320)
    unsigned* flags = (unsigned*)(SPs + 320);        // NBLK
    unsigned* rel   = flags + NBLK;                  // 1 (+pad to 256)
    int*   cnt    = (int*)(rel + 256);               // NB cursors (must start at 0)

    // zero flags + rel + cnt in one captured async memset
    hipMemsetAsync(flags, 0, (NBLK + 256 + NB) * sizeof(unsigned), stream);
    k_fused<<<NBLK, NTHR, 0, stream>>>(h, W, a, out,
        Wh2g, sv, wnv, wpv, sg,
        cs_neg, cs_pos, cs_sn, cs_sp,
        PN, SP, PNs, SPs,
        cnt, flags, rel);
}

// Round 17
// 89.951 us; speedup vs baseline: 1.5907x; 1.0235x over previous
//
#include <hip/hip_runtime.h>
#include <math.h>

#define NN 8192
#define KDIM 256
#define DD 64
#define NB 4096
#define NBLK 256
#define NTHR 512
#define RPB 32           // rows per block
#define CH 32            // sorted elements per chunk (= rows per block)
#define NCH 256          // chunks
#define LRALPHA 0.2f

__device__ __forceinline__ unsigned f2k(float f) {
    unsigned u = __float_as_uint(f);
    return u ^ ((u >> 31) ? 0xFFFFFFFFu : 0x80000000u);
}
__device__ __forceinline__ float k2f(unsigned k) {
    return __uint_as_float((k & 0x80000000u) ? (k ^ 0x80000000u) : ~k);
}
__device__ __forceinline__ unsigned bucket_of(unsigned key, unsigned kmin, float scale) {
    unsigned d = key - kmin;
    unsigned b = (unsigned)((float)d * scale);
    return b > (NB - 1) ? (NB - 1) : b;
}

// MALL-coherent bypass ops (PROVEN 92us R10/R15): relaxed agent-scope atomics ->
// global_load/store sc0 sc1 (L1/L2 bypass). BATCH-ISSUE loads. Do NOT use plain
// cached loads on cross-block data (R8/R9: +80us replay coherence-probe penalty).
// Do NOT use all-poll full barriers (R14: 256x poll contention).
__device__ __forceinline__ void  cstf(float* p, float v) { __hip_atomic_store(p, v, __ATOMIC_RELAXED, __HIP_MEMORY_SCOPE_AGENT); }
__device__ __forceinline__ float cldf(const float* p)    { return __hip_atomic_load((float*)p, __ATOMIC_RELAXED, __HIP_MEMORY_SCOPE_AGENT); }
__device__ __forceinline__ unsigned cldu(const unsigned* p) { return __hip_atomic_load((unsigned*)p, __ATOMIC_RELAXED, __HIP_MEMORY_SCOPE_AGENT); }
__device__ __forceinline__ void cstu(unsigned* p, unsigned v) { __hip_atomic_store(p, v, __ATOMIC_RELAXED, __HIP_MEMORY_SCOPE_AGENT); }

// Fence-free two-stage FULL grid barrier (proven R5/R7/R10) — used only where all
// blocks truly consume all blocks' data (barriers 1 and 2).
__device__ __forceinline__ void gridbar(unsigned* flags, unsigned* rel, unsigned phase) {
    asm volatile("s_waitcnt vmcnt(0)" ::: "memory");
    __syncthreads();
    const int t = threadIdx.x;
    if (blockIdx.x == 0) {
        if (t == 0)
            cstu(&flags[0], phase);
        if (t < NBLK) {
            while (cldu(&flags[t]) < phase)
                __builtin_amdgcn_s_sleep(1);
        }
        __syncthreads();
        if (t == 0)
            cstu(rel, phase);
    } else {
        if (t == 0) {
            cstu(&flags[blockIdx.x], phase);
            while (cldu(rel) < phase)
                __builtin_amdgcn_s_sleep(1);
        }
        __syncthreads();
    }
}

__global__ __launch_bounds__(NTHR, 2) void k_fused(
    const float* __restrict__ h, const float* __restrict__ W,
    const float* __restrict__ a, float* __restrict__ out,
    float* Wh2g, float* sv, float* wnv, float* wpv, float* sg,
    float* cs_neg, float* cs_pos, float* cs_sn, float* cs_sp,
    float* PN, float* SP, float* PNs, float* SPs,
    int* cnt, unsigned* flags, unsigned* rel, unsigned* done)
{
    __shared__ int      ls_bstart[NB + 1];     // persists P1 -> P4
    __shared__ float    ls_wh1[RPB];
    __shared__ float    ls_wh2[RPB];
    __shared__ unsigned ls_ra[8], ls_rb[8];
    __shared__ int      ls_wsum[8];
    __shared__ float    ls_cs[8][2 * DD];      // P2 reduce / P3 scan scratch
    __shared__ float    ls_css[16];
    __shared__ float    ls_M2, ls_scale;
    __shared__ unsigned ls_kmin;

    const int t = threadIdx.x, bid = blockIdx.x;
    const int wv = t >> 6, lane = t & 63;
    const int rowBase = bid * RPB;

    // ================= P0: GEMM; rows live in registers until scatter ======
    float myrow[4];
    {
        const int r0 = rowBase + wv * 4;
        float acc0 = 0.f, acc1 = 0.f, acc2 = 0.f, acc3 = 0.f;
        #pragma unroll 2
        for (int k4 = 0; k4 < KDIM / 4; ++k4) {
            float w0 = W[(4 * k4 + 0) * DD + lane];
            float w1 = W[(4 * k4 + 1) * DD + lane];
            float w2 = W[(4 * k4 + 2) * DD + lane];
            float w3 = W[(4 * k4 + 3) * DD + lane];
            float4 h0 = *(const float4*)(h + (size_t)(r0 + 0) * KDIM + 4 * k4);
            float4 h1 = *(const float4*)(h + (size_t)(r0 + 1) * KDIM + 4 * k4);
            float4 h2 = *(const float4*)(h + (size_t)(r0 + 2) * KDIM + 4 * k4);
            float4 h3 = *(const float4*)(h + (size_t)(r0 + 3) * KDIM + 4 * k4);
            acc0 = fmaf(h0.x, w0, acc0); acc0 = fmaf(h0.y, w1, acc0);
            acc0 = fmaf(h0.z, w2, acc0); acc0 = fmaf(h0.w, w3, acc0);
            acc1 = fmaf(h1.x, w0, acc1); acc1 = fmaf(h1.y, w1, acc1);
            acc1 = fmaf(h1.z, w2, acc1); acc1 = fmaf(h1.w, w3, acc1);
            acc2 = fmaf(h2.x, w0, acc2); acc2 = fmaf(h2.y, w1, acc2);
            acc2 = fmaf(h2.z, w2, acc2); acc2 = fmaf(h2.w, w3, acc2);
            acc3 = fmaf(h3.x, w0, acc3); acc3 = fmaf(h3.y, w1, acc3);
            acc3 = fmaf(h3.z, w2, acc3); acc3 = fmaf(h3.w, w3, acc3);
        }
        myrow[0] = acc0; myrow[1] = acc1; myrow[2] = acc2; myrow[3] = acc3;
        float a1 = a[lane], a2 = a[DD + lane];
        #pragma unroll
        for (int i = 0; i < 4; ++i) {
            float r1 = myrow[i] * a1, r2 = myrow[i] * a2;
            #pragma unroll
            for (int off = 32; off > 0; off >>= 1) {
                r1 += __shfl_xor(r1, off, 64);
                r2 += __shfl_xor(r2, off, 64);
            }
            if (lane == 0) {
                cstf(&Wh2g[r0 + i], r2);
                ls_wh1[wv * 4 + i] = r1;
                ls_wh2[wv * 4 + i] = r2;
            }
        }
    }
    gridbar(flags, rel, 1);

    // ================= P1: redundant minmax+hist+scan (LDS) + scatter =================
    for (int i = t; i < NB; i += NTHR) ls_bstart[i] = 0;
    float v16[16];
    #pragma unroll
    for (int q = 0; q < 16; ++q)                    // batch-issue 16 bypass loads
        v16[q] = cldf(&Wh2g[t + q * NTHR]);
    {
        unsigned lmin = 0xFFFFFFFFu, lmax = 0u;
        #pragma unroll
        for (int q = 0; q < 16; ++q) {
            unsigned k = f2k(v16[q]);
            lmin = min(lmin, k); lmax = max(lmax, k);
        }
        #pragma unroll
        for (int off = 32; off > 0; off >>= 1) {
            lmin = min(lmin, (unsigned)__shfl_xor((int)lmin, off, 64));
            lmax = max(lmax, (unsigned)__shfl_xor((int)lmax, off, 64));
        }
        if (lane == 0) { ls_ra[wv] = lmin; ls_rb[wv] = lmax; }
    }
    __syncthreads();
    if (t == 0) {
        unsigned mn = ls_ra[0], mx = ls_rb[0];
        for (int i = 1; i < 8; ++i) { mn = min(mn, ls_ra[i]); mx = max(mx, ls_rb[i]); }
        ls_kmin = mn;
        ls_scale = (float)NB / ((float)(mx - mn) + 1.0f);
        ls_M2 = k2f(mx);
    }
    __syncthreads();
    const unsigned kmin = ls_kmin;
    const float scale = ls_scale;
    const float M2 = ls_M2;

    #pragma unroll
    for (int q = 0; q < 16; ++q)
        atomicAdd(&ls_bstart[bucket_of(f2k(v16[q]), kmin, scale)], 1);
    __syncthreads();
    {
        int s[8]; int tot = 0;
        #pragma unroll
        for (int j = 0; j < 8; ++j) { s[j] = ls_bstart[8 * t + j]; tot += s[j]; }
        int x = tot;
        #pragma unroll
        for (int off = 1; off < 64; off <<= 1) {
            int y = __shfl_up(x, off, 64);
            if (lane >= off) x += y;
        }
        if (lane == 63) ls_wsum[wv] = x;
        __syncthreads();
        int woff = 0;
        for (int w2 = 0; w2 < wv; ++w2) woff += ls_wsum[w2];
        int acc = woff + x - tot;
        #pragma unroll
        for (int j = 0; j < 8; ++j) { ls_bstart[8 * t + j] = acc; acc += s[j]; }
        if (t == 0) ls_bstart[NB] = NN;
    }
    __syncthreads();
    // scatter: lanes 0-3 issue the 4 cursor RMWs concurrently; rows from registers
    {
        int posl = 0;
        if (lane < 4) {
            unsigned b = bucket_of(f2k(ls_wh2[wv * 4 + lane]), kmin, scale);
            posl = ls_bstart[b] + atomicAdd(&cnt[b], 1);
        }
        #pragma unroll
        for (int i = 0; i < 4; ++i) {
            int lr = wv * 4 + i;
            float x = ls_wh2[lr];
            int pos = __shfl(posl, i, 64);
            cstf(&sg[(size_t)pos * DD + lane], myrow[i]);
            if (lane == 0) {
                cstf(&sv[pos], x);
                cstf(&wnv[pos], expf(LRALPHA * (x - M2)));   // <= 1
                cstf(&wpv[pos], expf(x - M2));               // <= 1
            }
        }
    }
    gridbar(flags, rel, 2);

    // ================= P2: chunk sums — chunk bid = sorted rows [32*bid, 32*bid+32) ==
    {
        int base = bid * CH + wv * 4;
        float g4[4], wn4[4], wp4[4];
        #pragma unroll
        for (int kk = 0; kk < 4; ++kk) {            // batch-issue 12 loads
            int k = base + kk;
            g4[kk]  = cldf(&sg[(size_t)k * DD + lane]);
            wn4[kk] = cldf(&wnv[k]);
            wp4[kk] = cldf(&wpv[k]);
        }
        float an = 0.f, ap = 0.f, sn = 0.f, sp = 0.f;
        #pragma unroll
        for (int kk = 0; kk < 4; ++kk) {
            an = fmaf(wn4[kk], g4[kk], an); ap = fmaf(wp4[kk], g4[kk], ap);
            sn += wn4[kk]; sp += wp4[kk];
        }
        ls_cs[wv][lane] = an; ls_cs[wv][DD + lane] = ap;
        if (lane == 0) { ls_css[wv] = sn; ls_css[8 + wv] = sp; }
        __syncthreads();
        if (wv == 0) {
            float s = 0.f;
            #pragma unroll
            for (int w2 = 0; w2 < 8; ++w2) s += ls_cs[w2][lane];
            cstf(&cs_neg[bid * DD + lane], s);
            if (lane == 0) { float ss = 0.f; for (int w2 = 0; w2 < 8; ++w2) ss += ls_css[w2]; cstf(&cs_sn[bid], ss); }
        } else if (wv == 1) {
            float s = 0.f;
            #pragma unroll
            for (int w2 = 0; w2 < 8; ++w2) s += ls_cs[w2][DD + lane];
            cstf(&cs_pos[bid * DD + lane], s);
            if (lane == 0) { float ss = 0.f; for (int w2 = 0; w2 < 8; ++w2) ss += ls_css[8 + w2]; cstf(&cs_sp[bid], ss); }
        }
    }
    // ---- arrival-only sync: publish "my cs_* stores are visible" (NO full barrier;
    //      only blocks 0-2 consume cs_*, so only they poll arrivals) ----
    asm volatile("s_waitcnt vmcnt(0)" ::: "memory");
    __syncthreads();
    if (t == 0)
        cstu(&flags[bid], 3u);

    // ================= P3: blocks 0-2 poll arrivals + scan; others skip waiting =======
    if (bid == 0) {
        if (t < NBLK) { while (cldu(&flags[t]) < 3u) __builtin_amdgcn_s_sleep(1); }
        __syncthreads();
        // exclusive prefix of neg-weighted chunk vectors -> PN[0..256]
        const int c0 = wv * 32;
        float v[32];
        #pragma unroll
        for (int j = 0; j < 32; ++j) v[j] = cldf(&cs_neg[(c0 + j) * DD + lane]);  // batch
        float tot = 0.f;
        #pragma unroll
        for (int j = 0; j < 32; ++j) tot += v[j];
        ls_cs[wv][lane] = tot;
        __syncthreads();
        float acc = 0.f;
        for (int w2 = 0; w2 < wv; ++w2) acc += ls_cs[w2][lane];
        #pragma unroll
        for (int j = 0; j < 32; ++j) { cstf(&PN[(c0 + j) * DD + lane], acc); acc += v[j]; }
        if (wv == 7) cstf(&PN[NCH * DD + lane], acc);
        asm volatile("s_waitcnt vmcnt(0)" ::: "memory");
        __syncthreads();
        if (t == 0) cstu(&done[0], 1u);
    } else if (bid == 1) {
        if (t < NBLK) { while (cldu(&flags[t]) < 3u) __builtin_amdgcn_s_sleep(1); }
        __syncthreads();
        // inclusive suffix of pos-weighted chunk vectors -> SP[0..256]
        const int c0 = wv * 32;
        float v[32];
        #pragma unroll
        for (int j = 0; j < 32; ++j) v[j] = cldf(&cs_pos[(c0 + j) * DD + lane]);  // batch
        float tot = 0.f;
        #pragma unroll
        for (int j = 0; j < 32; ++j) tot += v[j];
        ls_cs[wv][lane] = tot;
        __syncthreads();
        float acc = 0.f;
        for (int w2 = wv + 1; w2 < 8; ++w2) acc += ls_cs[w2][lane];
        #pragma unroll
        for (int j = 31; j >= 0; --j) { acc += v[j]; cstf(&SP[(c0 + j) * DD + lane], acc); }
        if (wv == 7) cstf(&SP[NCH * DD + lane], 0.f);
        asm volatile("s_waitcnt vmcnt(0)" ::: "memory");
        __syncthreads();
        if (t == 0) cstu(&done[1], 1u);
    } else if (bid == 2) {
        if (t < NBLK) { while (cldu(&flags[t]) < 3u) __builtin_amdgcn_s_sleep(1); }
        __syncthreads();
        if (wv == 0) {          // scalar prefix
            float s[4];
            #pragma unroll
            for (int j = 0; j < 4; ++j) s[j] = cldf(&cs_sn[4 * lane + j]);
            float tot = s[0] + s[1] + s[2] + s[3];
            float x = tot;
            #pragma unroll
            for (int off = 1; off < 64; off <<= 1) {
                float y = __shfl_up(x, off, 64);
                if (lane >= off) x += y;
            }
            float acc = x - tot;
            #pragma unroll
            for (int j = 0; j < 4; ++j) { cstf(&PNs[4 * lane + j], acc); acc += s[j]; }
            if (lane == 63) cstf(&PNs[NCH], acc);
        } else if (wv == 1) {   // scalar suffix
            float s[4];
            #pragma unroll
            for (int j = 0; j < 4; ++j) s[j] = cldf(&cs_sp[4 * lane + j]);
            float tot = s[0] + s[1] + s[2] + s[3];
            float x = tot;
            #pragma unroll
            for (int off = 1; off < 64; off <<= 1) {
                float y = __shfl_down(x, off, 64);
                if (lane < 64 - off) x += y;
            }
            float acc = x - tot;   // sum over lanes > lane
            #pragma unroll
            for (int j = 3; j >= 0; --j) { acc += s[j]; cstf(&SPs[4 * lane + j], acc); }   // FIX: restored acc += s[j]
            if (lane == 63) cstf(&SPs[NCH], 0.f);
        }
        asm volatile("s_waitcnt vmcnt(0)" ::: "memory");
        __syncthreads();
        if (t == 0) cstu(&done[2], 1u);
    }

    // ---- correction precompute (all blocks; overlaps blocks 0-2's scans;
    //      depends only on post-scatter data, final since barrier 2) ----
    int c0f4[4], c1e4[4];
    float cn4[4], dn4[4], cp4[4], dp4[4];
    #pragma unroll
    for (int i = 0; i < 4; ++i) {
        float tt = -ls_wh1[wv * 4 + i];
        unsigned kt = f2k(tt);
        int p0 = 0, p1 = 0;
        if (kt >= kmin) {
            unsigned b = bucket_of(kt, kmin, scale);
            p0 = ls_bstart[b]; p1 = ls_bstart[b + 1];
        }
        int c0f = p0 >> 5, c1e = (p1 + 31) >> 5;     // CH = 32
        c0f4[i] = c0f; c1e4[i] = c1e;
        float nn_ = 0.f, dn_ = 0.f, np_ = 0.f, dp_ = 0.f;
        for (int base2 = c0f * CH; base2 < c1e * CH; base2 += 8) {
            float sv8[8], wn8[8], wp8[8], g8[8];
            #pragma unroll
            for (int jj = 0; jj < 8; ++jj) {        // batch-issue 32 loads
                int k = base2 + jj;
                sv8[jj] = cldf(&sv[k]);
                wn8[jj] = cldf(&wnv[k]);
                wp8[jj] = cldf(&wpv[k]);
                g8[jj]  = cldf(&sg[(size_t)k * DD + lane]);
            }
            #pragma unroll
            for (int jj = 0; jj < 8; ++jj) {
                if (sv8[jj] <= tt) { nn_ = fmaf(wn8[jj], g8[jj], nn_); dn_ += wn8[jj]; }
                else               { np_ = fmaf(wp8[jj], g8[jj], np_); dp_ += wp8[jj]; }
            }
        }
        cn4[i] = nn_; dn4[i] = dn_; cp4[i] = np_; dp4[i] = dp_;
    }

    // ---- one-way sync: wait for the 3 scan producers only ----
    if (t < 3) { while (cldu(&done[t]) < 1u) __builtin_amdgcn_s_sleep(1); }
    __syncthreads();

    // ================= P4: finalize — batched headers + math only =================
    float pn4[4], sp4[4], pns4[4], sps4[4];
    #pragma unroll
    for (int i = 0; i < 4; ++i) {                   // batch-issue 16 header loads
        pn4[i]  = cldf(&PN[c0f4[i] * DD + lane]);
        sp4[i]  = cldf(&SP[c1e4[i] * DD + lane]);
        pns4[i] = cldf(&PNs[c0f4[i]]);
        sps4[i] = cldf(&SPs[c1e4[i]]);
    }
    #pragma unroll
    for (int i = 0; i < 4; ++i) {
        int row = rowBase + wv * 4 + i;
        float w1 = ls_wh1[wv * 4 + i];
        float z = w1 + M2;                          // max_j (Wh1_i + Wh2_j)
        float m = (z >= 0.f) ? z : LRALPHA * z;     // lrelu(z) = exact row max
        float c1 = expf(z - m);                     // exponent <= 0
        float c2 = expf(LRALPHA * z - m);           // exponent <= 0
        float num = c2 * (pn4[i] + cn4[i]) + c1 * (sp4[i] + cp4[i]);
        float den = c2 * (pns4[i] + dn4[i]) + c1 * (sps4[i] + dp4[i]);
        float r = num / den;
        out[(size_t)row * DD + lane] = (r > 0.f) ? r : expm1f(r);   // elu
    }
}

extern "C" void kernel_launch(void* const* d_in, const int* in_sizes, int n_in,
                              void* d_out, int out_size, void* d_ws, size_t ws_size,
                              hipStream_t stream)
{
    const float* h = (const float*)d_in[0];
    // d_in[1] = adj (bool, unused by the reference computation)
    const float* W = (const float*)d_in[2];
    const float* a = (const float*)d_in[3];
    float* out = (float*)d_out;
    float* ws = (float*)d_ws;

    float* Wh2g   = ws;                              // NN
    float* sv     = Wh2g + NN;                       // NN
    float* wnv    = sv + NN;                         // NN
    float* wpv    = wnv + NN;                        // NN
    float* sg     = wpv + NN;                        // NN*DD (sorted Wh rows)
    float* cs_neg = sg + (size_t)NN * DD;            // NCH*DD
    float* cs_pos = cs_neg + NCH * DD;               // NCH*DD
    float* cs_sn  = cs_pos + NCH * DD;               // NCH
    float* cs_sp  = cs_sn + NCH;                     // NCH
    float* PN     = cs_sp + NCH;                     // (NCH+1)*DD
    float* SP     = PN + (NCH + 1) * DD;             // (NCH+1)*DD
    float* PNs    = SP + (NCH + 1) * DD;             // NCH+1 (pad 320)
    float* SPs    = PNs + 320;                       // NCH+1 (pad 320)
    unsigned* flags = (unsigned*)(SPs + 320);        // NBLK
    unsigned* rel   = flags + NBLK;                  // 1 (pad 64)
    unsigned* done  = rel + 64;                      // 3 (pad 64)
    int*   cnt    = (int*)(done + 64);               // NB cursors (must start at 0)

    // zero flags + rel + done + cnt in one captured async memset
    hipMemsetAsync(flags, 0, (NBLK + 64 + 64 + NB) * sizeof(unsigned), stream);
    k_fused<<<NBLK, NTHR, 0, stream>>>(h, W, a, out,
        Wh2g, sv, wnv, wpv, sg,
        cs_neg, cs_pos, cs_sn, cs_sp,
        PN, SP, PNs, SPs,
        cnt, flags, rel, done);
}